// Round 3
// baseline (5478.321 us; speedup 1.0000x reference)
//
#include <hip/hip_runtime.h>
#include <hip/hip_bf16.h>

#define N_USERS 100000
#define E_HYPER 50000
#define NNZ_E   800000
#define T_STEPS 8
#define DIM     64

// ---------------------------------------------------------------------------
// dtype-adaptive load: flag==1 -> buffer is fp32, flag==0 -> buffer is bf16
// ---------------------------------------------------------------------------
__device__ __forceinline__ float ld_in(const void* p, size_t i, int f32)
{
    return f32 ? ((const float*)p)[i]
               : __bfloat162float(((const __hip_bfloat16*)p)[i]);
}

// ---------------------------------------------------------------------------
// Kernel 0: detect input dtype. Genuine bf16 N(0,1/8) halfwords always have
// exponent <= 126; fp32 low-halfword mantissa garbage trips e>126 ~50%.
// ---------------------------------------------------------------------------
__global__ void k_detect(const unsigned short* __restrict__ raw, int* __restrict__ flag)
{
    __shared__ int cnt;
    if (threadIdx.x == 0) cnt = 0;
    __syncthreads();
    int c = 0;
    for (int i = threadIdx.x; i < 4096; i += blockDim.x) {
        int e = (raw[i] >> 7) & 0xFF;
        if (e > 126) c++;
    }
    atomicAdd(&cnt, c);
    __syncthreads();
    if (threadIdx.x == 0) *flag = (cnt > 64) ? 1 : 0;
}

// ---------------------------------------------------------------------------
// Kernel 0b: convert all small params to fp32 staging.
// layout in st (floats): W[0,4096) b[4096,4160) w1[4160,8256) b1[8256,8320)
//                        w2[8320,8384) b2[8384]
// ---------------------------------------------------------------------------
__global__ void k_convert_params(
    const void* W, const void* b, const void* w1, const void* b1,
    const void* w2, const void* b2, const int* __restrict__ flag,
    float* __restrict__ st)
{
    int f = *flag;
    int i = blockIdx.x * blockDim.x + threadIdx.x;
    if (i < 4096)          st[i] = ld_in(W,  i,        f);
    else if (i < 4160)     st[i] = ld_in(b,  i - 4096, f);
    else if (i < 8256)     st[i] = ld_in(w1, i - 4160, f);
    else if (i < 8320)     st[i] = ld_in(b1, i - 8256, f);
    else if (i < 8384)     st[i] = ld_in(w2, i - 8320, f);
    else if (i == 8384)    st[i] = ld_in(b2, 0,        f);
}

// ---------------------------------------------------------------------------
// Kernel 1: h = relu(user_emb @ W_conv + b_conv)  -> bf16 [N, D]
// ---------------------------------------------------------------------------
__global__ __launch_bounds__(256) void k_transform(
    const void* __restrict__ emb, const int* __restrict__ flag,
    const float* __restrict__ st, __hip_bfloat16* __restrict__ h)
{
    __shared__ float Wl[DIM * DIM];
    __shared__ float bl[DIM];
    for (int i = threadIdx.x; i < DIM * DIM; i += blockDim.x) Wl[i] = st[i];
    if (threadIdx.x < DIM) bl[threadIdx.x] = st[4096 + threadIdx.x];
    __syncthreads();

    int f = *flag;
    int gid = blockIdx.x * blockDim.x + threadIdx.x;
    int n = gid >> 6, j = gid & 63;
    if (n >= N_USERS) return;
    size_t base = (size_t)n * DIM;
    float acc = bl[j];
#pragma unroll
    for (int k = 0; k < DIM; ++k)
        acc += ld_in(emb, base + k, f) * Wl[k * DIM + j];
    h[base + j] = __float2bfloat16(fmaxf(acc, 0.f));
}

// ---------------------------------------------------------------------------
// Kernel 2: scatter node feats -> hyperedge sums (+ both counts)
// ---------------------------------------------------------------------------
__global__ __launch_bounds__(256) void k_scatter_n2e(
    const __hip_bfloat16* __restrict__ h,
    const int* __restrict__ nodes, const int* __restrict__ hyper,
    float* __restrict__ e_sum, float* __restrict__ e_cnt,
    float* __restrict__ n_cnt)
{
    long gid = (long)blockIdx.x * blockDim.x + threadIdx.x;
    int i = (int)(gid >> 6), j = (int)(gid & 63);
    if (i >= NNZ_E) return;
    int nd = nodes[i], hy = hyper[i];
    float v = __bfloat162float(h[(size_t)nd * DIM + j]);
    atomicAdd(&e_sum[(size_t)hy * DIM + j], v);
    if (j == 0) {
        atomicAdd(&e_cnt[hy], 1.f);
        atomicAdd(&n_cnt[nd], 1.f);
    }
}

// ---------------------------------------------------------------------------
// Kernel 3: e = e_sum / max(e_cnt, 1)  (in place)
// ---------------------------------------------------------------------------
__global__ __launch_bounds__(256) void k_norm_e(
    float* __restrict__ e_sum, const float* __restrict__ e_cnt)
{
    int gid = blockIdx.x * blockDim.x + threadIdx.x;
    if (gid >= E_HYPER * DIM) return;
    float c = e_cnt[gid >> 6];
    e_sum[gid] = e_sum[gid] / fmaxf(c, 1.f);
}

// ---------------------------------------------------------------------------
// Kernel 4: scatter hyperedge feats -> node sums
// ---------------------------------------------------------------------------
__global__ __launch_bounds__(256) void k_scatter_e2n(
    const float* __restrict__ e,
    const int* __restrict__ nodes, const int* __restrict__ hyper,
    float* __restrict__ n_sum)
{
    long gid = (long)blockIdx.x * blockDim.x + threadIdx.x;
    int i = (int)(gid >> 6), j = (int)(gid & 63);
    if (i >= NNZ_E) return;
    atomicAdd(&n_sum[(size_t)nodes[i] * DIM + j],
              e[(size_t)hyper[i] * DIM + j]);
}

// ---------------------------------------------------------------------------
// carry access (3 modes): f32-in-dout | f32-in-ws | bf16-in-dout
// ---------------------------------------------------------------------------
__device__ __forceinline__ float ld_carry(void* out, float* cws, size_t i,
                                          int f, int use_ws)
{
    if (f) return ((float*)out)[i];
    if (use_ws) return cws[i];
    return __bfloat162float(((__hip_bfloat16*)out)[i]);
}
__device__ __forceinline__ void st_carry(void* out, float* cws, size_t i,
                                         int f, int use_ws, int wr, float v)
{
    if (f) { ((float*)out)[i] = v; return; }
    if (use_ws) {
        cws[i] = v;
        if (wr) ((__hip_bfloat16*)out)[i] = __float2bfloat16(v);
        return;
    }
    ((__hip_bfloat16*)out)[i] = __float2bfloat16(v);
}

// ---------------------------------------------------------------------------
// Kernel 5 (t==0): carry = n_sum / max(n_cnt, 1)
// ---------------------------------------------------------------------------
__global__ __launch_bounds__(256) void k_norm_n_to_carry(
    const float* __restrict__ n_sum, const float* __restrict__ n_cnt,
    void* __restrict__ out, float* __restrict__ cws,
    const int* __restrict__ flag, int use_ws)
{
    int gid = blockIdx.x * blockDim.x + threadIdx.x;
    if (gid >= N_USERS * DIM) return;
    int f = *flag;
    float c = n_cnt[gid >> 6];
    st_carry(out, cws, gid, f, use_ws, 0, n_sum[gid] / fmaxf(c, 1.f));
}

// ---------------------------------------------------------------------------
// Kernel 6 (t>=1): dy = n_sum/max(cnt,1); carry = fuse(carry, dy)
// one 64-lane wave per row; w1 staged in LDS; row broadcast via shuffles.
// ---------------------------------------------------------------------------
__global__ __launch_bounds__(256) void k_fuse(
    void* __restrict__ out, float* __restrict__ cws,
    const float* __restrict__ n_sum, const float* __restrict__ n_cnt,
    const float* __restrict__ st, const int* __restrict__ flag,
    int use_ws, int write_out)
{
    __shared__ float w1l[DIM * DIM];
    __shared__ float b1l[DIM];
    __shared__ float w2l[DIM];
    __shared__ float b2s;
    for (int i = threadIdx.x; i < DIM * DIM; i += blockDim.x)
        w1l[i] = st[4160 + i];
    if (threadIdx.x < DIM) {
        b1l[threadIdx.x] = st[8256 + threadIdx.x];
        w2l[threadIdx.x] = st[8320 + threadIdx.x];
    }
    if (threadIdx.x == 0) b2s = st[8384];
    __syncthreads();

    int f = *flag;
    int wave = threadIdx.x >> 6;
    int lane = threadIdx.x & 63;
    int wavesTotal = gridDim.x * (blockDim.x >> 6);

    for (int row = blockIdx.x * (blockDim.x >> 6) + wave; row < N_USERS;
         row += wavesTotal) {
        size_t idx = (size_t)row * DIM + lane;
        float hid = ld_carry(out, cws, idx, f, use_ws);
        float c   = n_cnt[row];
        float dy  = n_sum[idx] / fmaxf(c, 1.f);

        float ah = 0.f, ad = 0.f;
#pragma unroll
        for (int k = 0; k < DIM; ++k) {
            float w = w1l[k * DIM + lane];
            ah += __shfl(hid, k, 64) * w;
            ad += __shfl(dy,  k, 64) * w;
        }
        float uh = tanhf(ah + b1l[lane]) * w2l[lane];
        float ud = tanhf(ad + b1l[lane]) * w2l[lane];
#pragma unroll
        for (int off = 32; off > 0; off >>= 1) {
            uh += __shfl_xor(uh, off, 64);
            ud += __shfl_xor(ud, off, 64);
        }
        float zh = uh + b2s, zd = ud + b2s;
        float m  = fmaxf(zh, zd);
        float ph = expf(zh - m), pd = expf(zd - m);
        float sh = ph / (ph + pd);
        float val = sh * hid + (1.f - sh) * dy;
        st_carry(out, cws, idx, f, use_ws, write_out, val);
    }
}

// ---------------------------------------------------------------------------
extern "C" void kernel_launch(void* const* d_in, const int* in_sizes, int n_in,
                              void* d_out, int out_size, void* d_ws,
                              size_t ws_size, hipStream_t stream)
{
    const void* user_emb = d_in[0];
    const void* W_conv   = d_in[1];
    const void* b_conv   = d_in[2];
    const void* fus_w1   = d_in[3];
    const void* fus_b1   = d_in[4];
    const void* fus_w2   = d_in[5];
    const void* fus_b2   = d_in[6];
    const int* edge_nodes = (const int*)d_in[7];
    const int* edge_hyper = (const int*)d_in[8];

    const size_t ND = (size_t)N_USERS * DIM;   // 6,400,000
    const size_t ED = (size_t)E_HYPER * DIM;   // 3,200,000

    // ws layout (fp32 word offsets):
    //   0        : flag (int)
    //   16       : params staging fp32 [8385] (pad to 8416)
    //   8416     : e_cnt [E]
    //   58416    : n_cnt [N]
    //   158416   : e_sum [ED]
    //   3358416  : n_sum [ND]
    //   9758416  : h bf16 [ND] (3.2M words)
    //   12958416 : optional fp32 carry [ND]
    float* ws = (float*)d_ws;
    int*   flag  = (int*)ws;
    float* st    = ws + 16;
    float* e_cnt = ws + 8416;
    float* n_cnt = ws + 58416;
    float* e_sum = ws + 158416;
    float* n_sum = ws + 3358416;
    __hip_bfloat16* h = (__hip_bfloat16*)(ws + 9758416);
    float* carry_ws   = ws + 12958416;

    const size_t need_ws_carry = (12958416 + ND) * 4;   // ~77.4 MB
    const int use_ws = (ws_size >= need_ws_carry) ? 1 : 0;

    k_detect<<<1, 256, 0, stream>>>((const unsigned short*)user_emb, flag);
    k_convert_params<<<(8385 + 255) / 256, 256, 0, stream>>>(
        W_conv, b_conv, fus_w1, fus_b1, fus_w2, fus_b2, flag, st);
    k_transform<<<(int)((ND + 255) / 256), 256, 0, stream>>>(
        user_emb, flag, st, h);

    const long scatter_threads = (long)NNZ_E * DIM;
    const int scatter_blocks = (int)((scatter_threads + 255) / 256);
    // one contiguous zero region: cnts + e_sum + n_sum
    const size_t zero_bytes = (size_t)(9758416 - 8416) * 4;

    for (int t = 0; t < T_STEPS; ++t) {
        const int* nodes = edge_nodes + (size_t)t * NNZ_E;
        const int* hyper = edge_hyper + (size_t)t * NNZ_E;

        hipMemsetAsync(e_cnt, 0, zero_bytes, stream);

        k_scatter_n2e<<<scatter_blocks, 256, 0, stream>>>(
            h, nodes, hyper, e_sum, e_cnt, n_cnt);
        k_norm_e<<<(int)((ED + 255) / 256), 256, 0, stream>>>(e_sum, e_cnt);
        k_scatter_e2n<<<scatter_blocks, 256, 0, stream>>>(
            e_sum, nodes, hyper, n_sum);

        if (t == 0) {
            k_norm_n_to_carry<<<(int)((ND + 255) / 256), 256, 0, stream>>>(
                n_sum, n_cnt, d_out, carry_ws, flag, use_ws);
        } else {
            k_fuse<<<(N_USERS + 3) / 4, 256, 0, stream>>>(
                d_out, carry_ws, n_sum, n_cnt, st, flag, use_ws,
                (t == T_STEPS - 1) ? 1 : 0);
        }
    }
}

// Round 4
// 3223.182 us; speedup vs baseline: 1.6997x; 1.6997x over previous
//
#include <hip/hip_runtime.h>
#include <hip/hip_bf16.h>

#define N_USERS 100000
#define E_HYPER 50000
#define NNZ_E   800000
#define T_STEPS 8
#define DIM     64

// ---------------------------------------------------------------------------
// dtype-adaptive load: flag==1 -> buffer is fp32, flag==0 -> buffer is bf16
// ---------------------------------------------------------------------------
__device__ __forceinline__ float ld_in(const void* p, size_t i, int f32)
{
    return f32 ? ((const float*)p)[i]
               : __bfloat162float(((const __hip_bfloat16*)p)[i]);
}

// ---------------------------------------------------------------------------
// Kernel 0: detect input dtype (bf16 N(0,1/8) halfwords have exponent<=126;
// fp32 low-halfword garbage trips e>126 ~50% of the time).
// ---------------------------------------------------------------------------
__global__ void k_detect(const unsigned short* __restrict__ raw, int* __restrict__ flag)
{
    __shared__ int cnt;
    if (threadIdx.x == 0) cnt = 0;
    __syncthreads();
    int c = 0;
    for (int i = threadIdx.x; i < 4096; i += blockDim.x) {
        int e = (raw[i] >> 7) & 0xFF;
        if (e > 126) c++;
    }
    atomicAdd(&cnt, c);
    __syncthreads();
    if (threadIdx.x == 0) *flag = (cnt > 64) ? 1 : 0;
}

// ---------------------------------------------------------------------------
// Kernel 0b: convert small params to fp32 staging.
// st: W[0,4096) b[4096,4160) w1[4160,8256) b1[8256,8320) w2[8320,8384) b2[8384]
// ---------------------------------------------------------------------------
__global__ void k_convert_params(
    const void* W, const void* b, const void* w1, const void* b1,
    const void* w2, const void* b2, const int* __restrict__ flag,
    float* __restrict__ st)
{
    int f = *flag;
    int i = blockIdx.x * blockDim.x + threadIdx.x;
    if (i < 4096)          st[i] = ld_in(W,  i,        f);
    else if (i < 4160)     st[i] = ld_in(b,  i - 4096, f);
    else if (i < 8256)     st[i] = ld_in(w1, i - 4160, f);
    else if (i < 8320)     st[i] = ld_in(b1, i - 8256, f);
    else if (i < 8384)     st[i] = ld_in(w2, i - 8320, f);
    else if (i == 8384)    st[i] = ld_in(b2, 0,        f);
}

// ---------------------------------------------------------------------------
// Kernel 1: h = relu(user_emb @ W_conv + b_conv) -> bf16 [N, D]
// wave per row (row read once); grid-stride
// ---------------------------------------------------------------------------
__global__ __launch_bounds__(256) void k_transform(
    const void* __restrict__ emb, const int* __restrict__ flag,
    const float* __restrict__ st, __hip_bfloat16* __restrict__ h)
{
    __shared__ float Wl[DIM * DIM];
    __shared__ float bl[DIM];
    for (int i = threadIdx.x; i < DIM * DIM; i += blockDim.x) Wl[i] = st[i];
    if (threadIdx.x < DIM) bl[threadIdx.x] = st[4096 + threadIdx.x];
    __syncthreads();

    int f = *flag;
    int wave = threadIdx.x >> 6, lane = threadIdx.x & 63;
    int wavesTotal = gridDim.x * (blockDim.x >> 6);
    for (int row = blockIdx.x * (blockDim.x >> 6) + wave; row < N_USERS;
         row += wavesTotal) {
        size_t base = (size_t)row * DIM;
        float v = ld_in(emb, base + lane, f);
        float acc = bl[lane];
#pragma unroll
        for (int k = 0; k < DIM; ++k)
            acc += __shfl(v, k, 64) * Wl[k * DIM + lane];
        h[base + lane] = __float2bfloat16(fmaxf(acc, 0.f));
    }
}

// ---------------------------------------------------------------------------
// Kernel 2: build per-segment linked lists for both directions in one pass.
// head_* pre-set to -1 via memset 0xFF.
// ---------------------------------------------------------------------------
__global__ __launch_bounds__(256) void k_build(
    const int* __restrict__ nodes, const int* __restrict__ hyper,
    int* __restrict__ head_e, int* __restrict__ next_e,
    int* __restrict__ head_n, int* __restrict__ next_n)
{
    int i = blockIdx.x * blockDim.x + threadIdx.x;
    if (i >= NNZ_E) return;
    next_e[i] = atomicExch(&head_e[hyper[i]], i);
    next_n[i] = atomicExch(&head_n[nodes[i]], i);
}

// ---------------------------------------------------------------------------
// Kernel 3: gather h rows per hyperedge, average -> e (bf16)
// one wave per hyperedge, chain walk (wave-uniform)
// ---------------------------------------------------------------------------
__global__ __launch_bounds__(256) void k_gather_e(
    const __hip_bfloat16* __restrict__ h,
    const int* __restrict__ nodes,
    const int* __restrict__ head_e, const int* __restrict__ next_e,
    __hip_bfloat16* __restrict__ e)
{
    int wave = threadIdx.x >> 6, lane = threadIdx.x & 63;
    int wavesTotal = gridDim.x * (blockDim.x >> 6);
    for (int seg = blockIdx.x * (blockDim.x >> 6) + wave; seg < E_HYPER;
         seg += wavesTotal) {
        int idx = head_e[seg];
        float acc = 0.f;
        int cnt = 0;
        while (idx >= 0) {
            int nxt = next_e[idx];
            int nd  = nodes[idx];
            acc += __bfloat162float(h[(size_t)nd * DIM + lane]);
            cnt++;
            idx = nxt;
        }
        e[(size_t)seg * DIM + lane] =
            __float2bfloat16(acc / (float)max(cnt, 1));
    }
}

// ---------------------------------------------------------------------------
// carry access (3 modes): f32-in-dout | f32-in-ws | bf16-in-dout
// ---------------------------------------------------------------------------
__device__ __forceinline__ float ld_carry(void* out, float* cws, size_t i,
                                          int f, int use_ws)
{
    if (f) return ((float*)out)[i];
    if (use_ws) return cws[i];
    return __bfloat162float(((__hip_bfloat16*)out)[i]);
}
__device__ __forceinline__ void st_carry(void* out, float* cws, size_t i,
                                         int f, int use_ws, int wr, float v)
{
    if (f) { ((float*)out)[i] = v; return; }
    if (use_ws) {
        cws[i] = v;
        if (wr) ((__hip_bfloat16*)out)[i] = __float2bfloat16(v);
        return;
    }
    ((__hip_bfloat16*)out)[i] = __float2bfloat16(v);
}

// ---------------------------------------------------------------------------
// Kernel 4: gather e rows per node, average -> dy (fp32) or carry (t==0)
// ---------------------------------------------------------------------------
__global__ __launch_bounds__(256) void k_gather_n(
    const __hip_bfloat16* __restrict__ e,
    const int* __restrict__ hyper,
    const int* __restrict__ head_n, const int* __restrict__ next_n,
    float* __restrict__ dy,
    void* __restrict__ out, float* __restrict__ cws,
    const int* __restrict__ flag, int use_ws, int to_carry)
{
    int f = *flag;
    int wave = threadIdx.x >> 6, lane = threadIdx.x & 63;
    int wavesTotal = gridDim.x * (blockDim.x >> 6);
    for (int seg = blockIdx.x * (blockDim.x >> 6) + wave; seg < N_USERS;
         seg += wavesTotal) {
        int idx = head_n[seg];
        float acc = 0.f;
        int cnt = 0;
        while (idx >= 0) {
            int nxt = next_n[idx];
            int hy  = hyper[idx];
            acc += __bfloat162float(e[(size_t)hy * DIM + lane]);
            cnt++;
            idx = nxt;
        }
        float v = acc / (float)max(cnt, 1);
        size_t o = (size_t)seg * DIM + lane;
        if (to_carry) st_carry(out, cws, o, f, use_ws, 0, v);
        else          dy[o] = v;
    }
}

// ---------------------------------------------------------------------------
// Kernel 5 (t>=1): carry = fuse(carry, dy); wave per row, grid-stride
// ---------------------------------------------------------------------------
__global__ __launch_bounds__(256) void k_fuse(
    void* __restrict__ out, float* __restrict__ cws,
    const float* __restrict__ dy_buf,
    const float* __restrict__ st, const int* __restrict__ flag,
    int use_ws, int write_out)
{
    __shared__ float w1l[DIM * DIM];
    __shared__ float b1l[DIM];
    __shared__ float w2l[DIM];
    __shared__ float b2s;
    for (int i = threadIdx.x; i < DIM * DIM; i += blockDim.x)
        w1l[i] = st[4160 + i];
    if (threadIdx.x < DIM) {
        b1l[threadIdx.x] = st[8256 + threadIdx.x];
        w2l[threadIdx.x] = st[8320 + threadIdx.x];
    }
    if (threadIdx.x == 0) b2s = st[8384];
    __syncthreads();

    int f = *flag;
    int wave = threadIdx.x >> 6, lane = threadIdx.x & 63;
    int wavesTotal = gridDim.x * (blockDim.x >> 6);

    for (int row = blockIdx.x * (blockDim.x >> 6) + wave; row < N_USERS;
         row += wavesTotal) {
        size_t idx = (size_t)row * DIM + lane;
        float hid = ld_carry(out, cws, idx, f, use_ws);
        float dy  = dy_buf[idx];

        float ah = 0.f, ad = 0.f;
#pragma unroll
        for (int k = 0; k < DIM; ++k) {
            float w = w1l[k * DIM + lane];
            ah += __shfl(hid, k, 64) * w;
            ad += __shfl(dy,  k, 64) * w;
        }
        float uh = tanhf(ah + b1l[lane]) * w2l[lane];
        float ud = tanhf(ad + b1l[lane]) * w2l[lane];
#pragma unroll
        for (int off = 32; off > 0; off >>= 1) {
            uh += __shfl_xor(uh, off, 64);
            ud += __shfl_xor(ud, off, 64);
        }
        float zh = uh + b2s, zd = ud + b2s;
        float m  = fmaxf(zh, zd);
        float ph = expf(zh - m), pd = expf(zd - m);
        float sh = ph / (ph + pd);
        float val = sh * hid + (1.f - sh) * dy;
        st_carry(out, cws, idx, f, use_ws, write_out, val);
    }
}

// ---------------------------------------------------------------------------
extern "C" void kernel_launch(void* const* d_in, const int* in_sizes, int n_in,
                              void* d_out, int out_size, void* d_ws,
                              size_t ws_size, hipStream_t stream)
{
    const void* user_emb = d_in[0];
    const void* W_conv   = d_in[1];
    const void* b_conv   = d_in[2];
    const void* fus_w1   = d_in[3];
    const void* fus_b1   = d_in[4];
    const void* fus_w2   = d_in[5];
    const void* fus_b2   = d_in[6];
    const int* edge_nodes = (const int*)d_in[7];
    const int* edge_hyper = (const int*)d_in[8];

    const size_t ND = (size_t)N_USERS * DIM;   // 6,400,000
    const size_t ED = (size_t)E_HYPER * DIM;   // 3,200,000

    // ws layout (fp32 word offsets), base ends at 12958464 (51.83 MB,
    // byte-identical to the round-3 proven-safe base):
    //   0        : flag
    //   16       : st fp32 [8448]
    //   8464     : head_e int [50000]   \ contiguous -> one 0xFF memset
    //   58464    : head_n int [100000]  /
    //   158464   : next_e int [800000]
    //   958464   : next_n int [800000]
    //   1758464  : e bf16 [ED] (1.6M words)
    //   3358464  : dy fp32 [ND]
    //   9758464  : h bf16 [ND] (3.2M words)
    //   12958464 : optional fp32 carry [ND]  -> 77.43 MB
    float* ws = (float*)d_ws;
    int*   flag   = (int*)ws;
    float* st     = ws + 16;
    int*   head_e = (int*)(ws + 8464);
    int*   head_n = (int*)(ws + 58464);
    int*   next_e = (int*)(ws + 158464);
    int*   next_n = (int*)(ws + 958464);
    __hip_bfloat16* e_buf = (__hip_bfloat16*)(ws + 1758464);
    float* dy_buf = ws + 3358464;
    __hip_bfloat16* h = (__hip_bfloat16*)(ws + 9758464);
    float* carry_ws   = ws + 12958464;

    const size_t need_ws_carry = (12958464 + ND) * 4;
    const int use_ws = (ws_size >= need_ws_carry) ? 1 : 0;

    k_detect<<<1, 256, 0, stream>>>((const unsigned short*)user_emb, flag);
    k_convert_params<<<(8385 + 255) / 256, 256, 0, stream>>>(
        W_conv, b_conv, fus_w1, fus_b1, fus_w2, fus_b2, flag, st);
    k_transform<<<1024, 256, 0, stream>>>(user_emb, flag, st, h);

    for (int t = 0; t < T_STEPS; ++t) {
        const int* nodes = edge_nodes + (size_t)t * NNZ_E;
        const int* hyper = edge_hyper + (size_t)t * NNZ_E;

        // heads = -1
        hipMemsetAsync(head_e, 0xFF, (size_t)(E_HYPER + N_USERS) * 4, stream);

        k_build<<<(NNZ_E + 255) / 256, 256, 0, stream>>>(
            nodes, hyper, head_e, next_e, head_n, next_n);
        k_gather_e<<<2048, 256, 0, stream>>>(h, nodes, head_e, next_e, e_buf);
        k_gather_n<<<2048, 256, 0, stream>>>(
            e_buf, hyper, head_n, next_n, dy_buf,
            d_out, carry_ws, flag, use_ws, (t == 0) ? 1 : 0);

        if (t > 0) {
            k_fuse<<<1024, 256, 0, stream>>>(
                d_out, carry_ws, dy_buf, st, flag, use_ws,
                (t == T_STEPS - 1) ? 1 : 0);
        }
    }
}

// Round 5
// 2013.902 us; speedup vs baseline: 2.7203x; 1.6005x over previous
//
#include <hip/hip_runtime.h>
#include <hip/hip_bf16.h>

#define N_USERS 100000
#define E_HYPER 50000
#define NNZ_E   800000
#define T_STEPS 8
#define DIM     64

typedef __bf16 bf16x8 __attribute__((ext_vector_type(8)));
typedef float  f32x4  __attribute__((ext_vector_type(4)));

// ---------------------------------------------------------------------------
// dtype-adaptive load: flag==1 -> buffer is fp32, flag==0 -> buffer is bf16
// ---------------------------------------------------------------------------
__device__ __forceinline__ float ld_in(const void* p, size_t i, int f32)
{
    return f32 ? ((const float*)p)[i]
               : __bfloat162float(((const __hip_bfloat16*)p)[i]);
}

// ---------------------------------------------------------------------------
// Kernel 0: detect input dtype (bf16 N(0,1/8) halfwords have exponent<=126;
// fp32 low-halfword garbage trips e>126 ~50% of the time).
// ---------------------------------------------------------------------------
__global__ void k_detect(const unsigned short* __restrict__ raw, int* __restrict__ flag)
{
    __shared__ int cnt;
    if (threadIdx.x == 0) cnt = 0;
    __syncthreads();
    int c = 0;
    for (int i = threadIdx.x; i < 4096; i += blockDim.x) {
        int e = (raw[i] >> 7) & 0xFF;
        if (e > 126) c++;
    }
    atomicAdd(&cnt, c);
    __syncthreads();
    if (threadIdx.x == 0) *flag = (cnt > 64) ? 1 : 0;
}

// ---------------------------------------------------------------------------
// Kernel 0b: convert small params to fp32 staging.
// st: W[0,4096) b[4096,4160) w1[4160,8256) b1[8256,8320) w2[8320,8384) b2[8384]
// ---------------------------------------------------------------------------
__global__ void k_convert_params(
    const void* W, const void* b, const void* w1, const void* b1,
    const void* w2, const void* b2, const int* __restrict__ flag,
    float* __restrict__ st)
{
    int f = *flag;
    int i = blockIdx.x * blockDim.x + threadIdx.x;
    if (i < 4096)          st[i] = ld_in(W,  i,        f);
    else if (i < 4160)     st[i] = ld_in(b,  i - 4096, f);
    else if (i < 8256)     st[i] = ld_in(w1, i - 4160, f);
    else if (i < 8320)     st[i] = ld_in(b1, i - 8256, f);
    else if (i < 8384)     st[i] = ld_in(w2, i - 8320, f);
    else if (i == 8384)    st[i] = ld_in(b2, 0,        f);
}

// ---------------------------------------------------------------------------
// Kernel 1: h = relu(user_emb @ W_conv + b_conv) -> bf16 [N, D]
// wave per row; grid-stride (single launch, not hot)
// ---------------------------------------------------------------------------
__global__ __launch_bounds__(256) void k_transform(
    const void* __restrict__ emb, const int* __restrict__ flag,
    const float* __restrict__ st, __hip_bfloat16* __restrict__ h)
{
    __shared__ float Wl[DIM * DIM];
    __shared__ float bl[DIM];
    for (int i = threadIdx.x; i < DIM * DIM; i += blockDim.x) Wl[i] = st[i];
    if (threadIdx.x < DIM) bl[threadIdx.x] = st[4096 + threadIdx.x];
    __syncthreads();

    int f = *flag;
    int wave = threadIdx.x >> 6, lane = threadIdx.x & 63;
    int wavesTotal = gridDim.x * (blockDim.x >> 6);
    for (int row = blockIdx.x * (blockDim.x >> 6) + wave; row < N_USERS;
         row += wavesTotal) {
        size_t base = (size_t)row * DIM;
        float v = ld_in(emb, base + lane, f);
        float acc = bl[lane];
#pragma unroll
        for (int k = 0; k < DIM; ++k)
            acc += __shfl(v, k, 64) * Wl[k * DIM + lane];
        h[base + lane] = __float2bfloat16(fmaxf(acc, 0.f));
    }
}

// ---------------------------------------------------------------------------
// Kernel 2: build per-segment linked lists for both directions in one pass.
// head_* pre-set to -1 via memset 0xFF.
// ---------------------------------------------------------------------------
__global__ __launch_bounds__(256) void k_build(
    const int* __restrict__ nodes, const int* __restrict__ hyper,
    int* __restrict__ head_e, int* __restrict__ next_e,
    int* __restrict__ head_n, int* __restrict__ next_n)
{
    int i = blockIdx.x * blockDim.x + threadIdx.x;
    if (i >= NNZ_E) return;
    next_e[i] = atomicExch(&head_e[hyper[i]], i);
    next_n[i] = atomicExch(&head_n[nodes[i]], i);
}

// ---------------------------------------------------------------------------
// Kernel 3: gather h rows per hyperedge, average -> e (bf16)
// one wave walks 4 chains concurrently (4x memory-level parallelism)
// ---------------------------------------------------------------------------
__global__ __launch_bounds__(256) void k_gather_e(
    const __hip_bfloat16* __restrict__ h,
    const int* __restrict__ nodes,
    const int* __restrict__ head_e, const int* __restrict__ next_e,
    __hip_bfloat16* __restrict__ e)
{
    int lane = threadIdx.x & 63;
    int wid = blockIdx.x * (blockDim.x >> 6) + (threadIdx.x >> 6);
    int nW  = gridDim.x * (blockDim.x >> 6);
    for (int s0 = wid * 4; s0 < E_HYPER; s0 += nW * 4) {
        int idx[4]; float acc[4]; int cnt[4];
#pragma unroll
        for (int c = 0; c < 4; ++c) {
            int sg = s0 + c;
            idx[c] = (sg < E_HYPER) ? head_e[sg] : -1;
            acc[c] = 0.f; cnt[c] = 0;
        }
        while (idx[0] >= 0 || idx[1] >= 0 || idx[2] >= 0 || idx[3] >= 0) {
            int nxt[4], nd[4];
#pragma unroll
            for (int c = 0; c < 4; ++c)
                if (idx[c] >= 0) { nxt[c] = next_e[idx[c]]; nd[c] = nodes[idx[c]]; }
#pragma unroll
            for (int c = 0; c < 4; ++c)
                if (idx[c] >= 0) {
                    acc[c] += __bfloat162float(h[(size_t)nd[c] * DIM + lane]);
                    cnt[c]++; idx[c] = nxt[c];
                }
        }
#pragma unroll
        for (int c = 0; c < 4; ++c) {
            int sg = s0 + c;
            if (sg < E_HYPER)
                e[(size_t)sg * DIM + lane] =
                    __float2bfloat16(acc[c] / (float)max(cnt[c], 1));
        }
    }
}

// ---------------------------------------------------------------------------
// carry access (3 modes): f32-in-dout | f32-in-ws | bf16-in-dout
// ---------------------------------------------------------------------------
__device__ __forceinline__ float ld_carry(void* out, float* cws, size_t i,
                                          int f, int use_ws)
{
    if (f) return ((float*)out)[i];
    if (use_ws) return cws[i];
    return __bfloat162float(((__hip_bfloat16*)out)[i]);
}
__device__ __forceinline__ void st_carry(void* out, float* cws, size_t i,
                                         int f, int use_ws, int wr, float v)
{
    if (f) { ((float*)out)[i] = v; return; }
    if (use_ws) {
        cws[i] = v;
        if (wr) ((__hip_bfloat16*)out)[i] = __float2bfloat16(v);
        return;
    }
    ((__hip_bfloat16*)out)[i] = __float2bfloat16(v);
}

// ---------------------------------------------------------------------------
// Kernel 4: gather e rows per node, average -> dy (fp32) or carry (t==0)
// 4 chains per wave
// ---------------------------------------------------------------------------
__global__ __launch_bounds__(256) void k_gather_n(
    const __hip_bfloat16* __restrict__ e,
    const int* __restrict__ hyper,
    const int* __restrict__ head_n, const int* __restrict__ next_n,
    float* __restrict__ dy,
    void* __restrict__ out, float* __restrict__ cws,
    const int* __restrict__ flag, int use_ws, int to_carry)
{
    int f = *flag;
    int lane = threadIdx.x & 63;
    int wid = blockIdx.x * (blockDim.x >> 6) + (threadIdx.x >> 6);
    int nW  = gridDim.x * (blockDim.x >> 6);
    for (int s0 = wid * 4; s0 < N_USERS; s0 += nW * 4) {
        int idx[4]; float acc[4]; int cnt[4];
#pragma unroll
        for (int c = 0; c < 4; ++c) {
            int sg = s0 + c;
            idx[c] = (sg < N_USERS) ? head_n[sg] : -1;
            acc[c] = 0.f; cnt[c] = 0;
        }
        while (idx[0] >= 0 || idx[1] >= 0 || idx[2] >= 0 || idx[3] >= 0) {
            int nxt[4], hy[4];
#pragma unroll
            for (int c = 0; c < 4; ++c)
                if (idx[c] >= 0) { nxt[c] = next_n[idx[c]]; hy[c] = hyper[idx[c]]; }
#pragma unroll
            for (int c = 0; c < 4; ++c)
                if (idx[c] >= 0) {
                    acc[c] += __bfloat162float(e[(size_t)hy[c] * DIM + lane]);
                    cnt[c]++; idx[c] = nxt[c];
                }
        }
#pragma unroll
        for (int c = 0; c < 4; ++c) {
            int sg = s0 + c;
            if (sg < N_USERS) {
                float v = acc[c] / (float)max(cnt[c], 1);
                size_t o = (size_t)sg * DIM + lane;
                if (to_carry) st_carry(out, cws, o, f, use_ws, 0, v);
                else          dy[o] = v;
            }
        }
    }
}

// ---------------------------------------------------------------------------
// Kernel 5 (t>=1): carry = fuse(carry, dy) via MFMA 16x16x32 bf16.
// One wave per 16-row tile. w1 held as B-frags in VGPRs. Score matmul in
// bf16 (fp32 accum); elementwise blend uses fp32 hid/dy. b2 cancels in the
// 2-way softmax. N_USERS % 16 == 0.
// ---------------------------------------------------------------------------
__global__ __launch_bounds__(256) void k_fuse_mfma(
    void* __restrict__ dout, float* __restrict__ cws,
    const float* __restrict__ dy_buf,
    const float* __restrict__ st, const int* __restrict__ flag,
    int use_ws, int write_out)
{
    int f = *flag;
    float* cf = f ? (float*)dout : (use_ws ? cws : (float*)0);
    __hip_bfloat16* cb = (__hip_bfloat16*)dout;

    int lane = threadIdx.x & 63;
    int quad = lane >> 4;
    int m    = lane & 15;

    // B-fragments of w1: lane holds w1[k = kb*32+quad*8+j][n = nt*16+m]
    bf16x8 bw[4][2];
    float b1v[4], w2v[4];
#pragma unroll
    for (int nt = 0; nt < 4; ++nt) {
#pragma unroll
        for (int kb = 0; kb < 2; ++kb)
#pragma unroll
            for (int j = 0; j < 8; ++j) {
                int k = kb * 32 + quad * 8 + j;
                bw[nt][kb][j] = (__bf16)st[4160 + k * 64 + nt * 16 + m];
            }
        b1v[nt] = st[8256 + nt * 16 + m];
        w2v[nt] = st[8320 + nt * 16 + m];
    }

    int wid = blockIdx.x * (blockDim.x >> 6) + (threadIdx.x >> 6);
    int nW  = gridDim.x * (blockDim.x >> 6);
    const int NT = N_USERS / 16;

    for (int tile = wid; tile < NT; tile += nW) {
        int row = tile * 16 + m;
        size_t base = (size_t)row * DIM;

        float hidf[2][8], dyf[2][8];
        if (cf) {
            const f32x4* cp = (const f32x4*)(cf + base);
            const f32x4* dp = (const f32x4*)(dy_buf + base);
#pragma unroll
            for (int kb = 0; kb < 2; ++kb) {
                f32x4 a = cp[kb * 8 + quad * 2], b = cp[kb * 8 + quad * 2 + 1];
                f32x4 c = dp[kb * 8 + quad * 2], d = dp[kb * 8 + quad * 2 + 1];
#pragma unroll
                for (int j = 0; j < 4; ++j) {
                    hidf[kb][j] = a[j]; hidf[kb][4 + j] = b[j];
                    dyf[kb][j]  = c[j]; dyf[kb][4 + j]  = d[j];
                }
            }
        } else {
#pragma unroll
            for (int kb = 0; kb < 2; ++kb)
#pragma unroll
                for (int j = 0; j < 8; ++j) {
                    int k = kb * 32 + quad * 8 + j;
                    hidf[kb][j] = __bfloat162float(cb[base + k]);
                    dyf[kb][j]  = dy_buf[base + k];
                }
        }

        bf16x8 ah[2], ad[2];
#pragma unroll
        for (int kb = 0; kb < 2; ++kb)
#pragma unroll
            for (int j = 0; j < 8; ++j) {
                ah[kb][j] = (__bf16)hidf[kb][j];
                ad[kb][j] = (__bf16)dyf[kb][j];
            }

        float zh[4] = {0.f, 0.f, 0.f, 0.f};
        float zd[4] = {0.f, 0.f, 0.f, 0.f};
#pragma unroll
        for (int nt = 0; nt < 4; ++nt) {
            f32x4 acch = {0.f, 0.f, 0.f, 0.f};
            f32x4 accd = {0.f, 0.f, 0.f, 0.f};
#pragma unroll
            for (int kb = 0; kb < 2; ++kb) {
                acch = __builtin_amdgcn_mfma_f32_16x16x32_bf16(ah[kb], bw[nt][kb], acch, 0, 0, 0);
                accd = __builtin_amdgcn_mfma_f32_16x16x32_bf16(ad[kb], bw[nt][kb], accd, 0, 0, 0);
            }
#pragma unroll
            for (int reg = 0; reg < 4; ++reg) {
                zh[reg] += tanhf(acch[reg] + b1v[nt]) * w2v[nt];
                zd[reg] += tanhf(accd[reg] + b1v[nt]) * w2v[nt];
            }
        }
        // reduce over the 16 cols within each quad (lanes quad*16..+15)
        float s[4];
#pragma unroll
        for (int reg = 0; reg < 4; ++reg) {
#pragma unroll
            for (int off = 1; off < 16; off <<= 1) {
                zh[reg] += __shfl_xor(zh[reg], off, 64);
                zd[reg] += __shfl_xor(zd[reg], off, 64);
            }
            float mm = fmaxf(zh[reg], zd[reg]);
            float eh = expf(zh[reg] - mm), ed = expf(zd[reg] - mm);
            s[reg] = eh / (eh + ed);   // lane holds s for row quad*4+reg
        }
        // redistribute: A-layout row = m; source quad = m>>2, reg = m&3
        int srcl = (m >> 2) * 16;
        float s0 = __shfl(s[0], srcl, 64), s1 = __shfl(s[1], srcl, 64);
        float s2 = __shfl(s[2], srcl, 64), s3 = __shfl(s[3], srcl, 64);
        int r3 = m & 3;
        float sv = (r3 == 0) ? s0 : (r3 == 1) ? s1 : (r3 == 2) ? s2 : s3;

        if (cf) {
            f32x4* cp = (f32x4*)(cf + base);
#pragma unroll
            for (int kb = 0; kb < 2; ++kb) {
                f32x4 v0, v1;
#pragma unroll
                for (int j = 0; j < 4; ++j) {
                    v0[j] = sv * hidf[kb][j]     + (1.f - sv) * dyf[kb][j];
                    v1[j] = sv * hidf[kb][4 + j] + (1.f - sv) * dyf[kb][4 + j];
                }
                cp[kb * 8 + quad * 2]     = v0;
                cp[kb * 8 + quad * 2 + 1] = v1;
                if (write_out && !f) {
#pragma unroll
                    for (int j = 0; j < 4; ++j) {
                        int k = kb * 32 + quad * 8 + j;
                        cb[base + k]     = __float2bfloat16(v0[j]);
                        cb[base + k + 4] = __float2bfloat16(v1[j]);
                    }
                }
            }
        } else {
#pragma unroll
            for (int kb = 0; kb < 2; ++kb)
#pragma unroll
                for (int j = 0; j < 8; ++j) {
                    int k = kb * 32 + quad * 8 + j;
                    float v = sv * hidf[kb][j] + (1.f - sv) * dyf[kb][j];
                    cb[base + k] = __float2bfloat16(v);
                }
        }
    }
}

// ---------------------------------------------------------------------------
extern "C" void kernel_launch(void* const* d_in, const int* in_sizes, int n_in,
                              void* d_out, int out_size, void* d_ws,
                              size_t ws_size, hipStream_t stream)
{
    const void* user_emb = d_in[0];
    const void* W_conv   = d_in[1];
    const void* b_conv   = d_in[2];
    const void* fus_w1   = d_in[3];
    const void* fus_b1   = d_in[4];
    const void* fus_w2   = d_in[5];
    const void* fus_b2   = d_in[6];
    const int* edge_nodes = (const int*)d_in[7];
    const int* edge_hyper = (const int*)d_in[8];

    const size_t ND = (size_t)N_USERS * DIM;   // 6,400,000

    // ws layout (fp32 word offsets) — identical to proven R4 base (51.83 MB):
    //   0        : flag
    //   16       : st fp32 [8448]
    //   8464     : head_e int [50000]   \ contiguous -> one 0xFF memset
    //   58464    : head_n int [100000]  /
    //   158464   : next_e int [800000]
    //   958464   : next_n int [800000]
    //   1758464  : e bf16 [ED]
    //   3358464  : dy fp32 [ND]
    //   9758464  : h bf16 [ND]
    //   12958464 : optional fp32 carry [ND]  -> 77.43 MB
    float* ws = (float*)d_ws;
    int*   flag   = (int*)ws;
    float* st     = ws + 16;
    int*   head_e = (int*)(ws + 8464);
    int*   head_n = (int*)(ws + 58464);
    int*   next_e = (int*)(ws + 158464);
    int*   next_n = (int*)(ws + 958464);
    __hip_bfloat16* e_buf = (__hip_bfloat16*)(ws + 1758464);
    float* dy_buf = ws + 3358464;
    __hip_bfloat16* h = (__hip_bfloat16*)(ws + 9758464);
    float* carry_ws   = ws + 12958464;

    const size_t need_ws_carry = (12958464 + ND) * 4;
    const int use_ws = (ws_size >= need_ws_carry) ? 1 : 0;

    k_detect<<<1, 256, 0, stream>>>((const unsigned short*)user_emb, flag);
    k_convert_params<<<(8385 + 255) / 256, 256, 0, stream>>>(
        W_conv, b_conv, fus_w1, fus_b1, fus_w2, fus_b2, flag, st);
    k_transform<<<1024, 256, 0, stream>>>(user_emb, flag, st, h);

    for (int t = 0; t < T_STEPS; ++t) {
        const int* nodes = edge_nodes + (size_t)t * NNZ_E;
        const int* hyper = edge_hyper + (size_t)t * NNZ_E;

        hipMemsetAsync(head_e, 0xFF, (size_t)(E_HYPER + N_USERS) * 4, stream);

        k_build<<<(NNZ_E + 255) / 256, 256, 0, stream>>>(
            nodes, hyper, head_e, next_e, head_n, next_n);
        // E/4 chains per wave: 12500 waves -> 3125 blocks
        k_gather_e<<<3125, 256, 0, stream>>>(h, nodes, head_e, next_e, e_buf);
        // N/4 chains per wave: 25000 waves -> 6250 blocks
        k_gather_n<<<6250, 256, 0, stream>>>(
            e_buf, hyper, head_n, next_n, dy_buf,
            d_out, carry_ws, flag, use_ws, (t == 0) ? 1 : 0);

        if (t > 0) {
            k_fuse_mfma<<<1024, 256, 0, stream>>>(
                d_out, carry_ws, dy_buf, st, flag, use_ws,
                (t == T_STEPS - 1) ? 1 : 0);
        }
    }
}